// Round 11
// baseline (149.629 us; speedup 1.0000x reference)
//
#include <hip/hip_runtime.h>
#include <stdint.h>

// MemoryEfficientBSpline: out[b,o,p] = sum_i sum_g hat_g(nx[b,i,p]) * coef[b,o,i,g]
// hat_g(nx) = max(0, 1 - |nx - g|),  nx = clamp(x*2.5+2.5, 0, 5) in [0,5], G=6.
// Batched GEMM M=64(o) x N=36864(p) x K=384(i*G) via mfma_f32_16x16x32_f16.
//
// v12: ZERO in-loop global memory. Every prior variant (v0-v11, all pinned at
// 54-76us with every pipe <30% busy) shared a per-chunk load->drain->compute
// cycle; with ~2 waves/SIMD each drain stalls all resident waves at once.
// Now the whole 48KB x-tile is staged ONCE in the prologue:
//   - coalesced dwordx4 (wave w owns rows 16w..16w+15; lanes 0-47 cover one
//     768B row per instr), clamp in f32, cvt_pkrtz to packed (i-even,i-odd)
//     f16 pairs in NX[32][196] u32 (25KB; main-loop read = 32 distinct banks
//     + 2x broadcast per instr = conflict-free; f16-nx numerics proven by v9).
//   - main loop: pure LDS+VALU+MFMA, no waits, no barriers, no inline asm;
//     bu math = 4 packed-f16 VALU per pair (ds_read_b32 delivers ready half2).
//   - keeps v11's proven epilogue (LDS-transpose overlay + nt dwordx4 stores,
//     WRITE exactly 72MB) and coef staging verbatim. 3 barriers total.
// LDS 75.3KB -> 2 blocks/CU (same as v11's measured occupancy: isolates the
// structural change from occupancy).

typedef __fp16 half8_t __attribute__((ext_vector_type(8)));
typedef __fp16 half2_t __attribute__((ext_vector_type(2)));
typedef float f32x4 __attribute__((ext_vector_type(4)));
typedef uint32_t u32x4 __attribute__((ext_vector_type(4)));

#define NBATCH 8
#define OD 64
#define ID 64
#define PIX 36864          // 192*192
#define NG 6
#define PT 192             // pixels per block tile (4 waves x 48)
#define KI 16              // i per chunk
#define NCHUNK 4           // 4 * 16 = 64 = ID
#define KC (KI * NG)       // 96 k-values per chunk (g-major: k = g*16 + iof)
#define AROW 392           // coef f16 row stride: 384 used + 8 pad
#define XSTR 196           // NX u32 row stride (196%32=4: read rows spread 4 banks)
#define SROW 196           // epilogue f32 row stride (16B-aligned, 2-way banks)
#define PTILES (PIX / PT)  // 192 p-tiles per batch

__global__ __launch_bounds__(256, 2)
void kan_mfma(const float* __restrict__ x, const float* __restrict__ coef,
              float* __restrict__ out) {
  const int t = threadIdx.x;
  const int lane = t & 63;
  const int wave = t >> 6;      // 0..3, owns p sub-range [wave*48, wave*48+48)
  const int q8 = lane >> 4;     // 0..3
  const int col = lane & 15;

  const int bid = blockIdx.x;
  const int b = bid / PTILES;   // same-b blocks contiguous -> coef L2 locality
  const int ptile = bid % PTILES;
  const int p0 = ptile * PT;

  __shared__ __fp16 A_lds[OD][AROW] __attribute__((aligned(16)));   // 50176 B
  __shared__ uint32_t NX[2 * KI][XSTR] __attribute__((aligned(16))); // 25088 B

  // ---- Phase A: coalesced x-tile loads (issue first; latency hides under
  // coef staging). Wave w rows 16w..16w+15; lane<48 takes 16B at float 4*lane.
  f32x4 xrow[16];
  const float* xbase = x + (size_t)b * ID * PIX + p0;
  if (lane < 48) {
#pragma unroll
    for (int k = 0; k < 16; ++k)
      xrow[k] = *(const f32x4*)(xbase + (size_t)(wave * 16 + k) * PIX + lane * 4);
  }

  // ---- coef staging (verbatim from v6/v11, proven): g-major f16 ----
  {
    const int o = t >> 2;
    const int c = t & 3;
    const float* crow = coef + (size_t)b * (OD * ID * NG) + o * (ID * NG) + c * KC;
    __fp16* arow = &A_lds[o][c * KC];
#pragma unroll
    for (int blk = 0; blk < 8; ++blk) {  // 2 iof's per blk: src r = iof*6+g, r+6
      f32x4 va = ((const f32x4*)crow)[blk * 3 + 0];
      f32x4 vb = ((const f32x4*)crow)[blk * 3 + 1];
      f32x4 vc = ((const f32x4*)crow)[blk * 3 + 2];
      const float lo[NG] = {va[0], va[1], va[2], va[3], vb[0], vb[1]};
      const float hi[NG] = {vb[2], vb[3], vc[0], vc[1], vc[2], vc[3]};
#pragma unroll
      for (int g = 0; g < NG; ++g) {
        half2_t h2 = __builtin_amdgcn_cvt_pkrtz(lo[g], hi[g]);
        *(half2_t*)&arow[g * KI + blk * 2] = h2;  // 4B-aligned b32 write
      }
    }
  }

  // ---- Phase B: clamp, pack (i-even, i-odd) f16 pairs, write NX ----
  if (lane < 48) {
#pragma unroll
    for (int pr = 0; pr < 8; ++pr) {
      u32x4 w4;
#pragma unroll
      for (int j = 0; j < 4; ++j) {
        float e = fminf(fmaxf(xrow[2 * pr][j] * 2.5f + 2.5f, 0.f), 5.f);
        float o = fminf(fmaxf(xrow[2 * pr + 1][j] * 2.5f + 2.5f, 0.f), 5.f);
        union { half2_t h; uint32_t u; } cv;
        cv.h = __builtin_amdgcn_cvt_pkrtz(e, o);  // lo=even-i, hi=odd-i
        w4[j] = cv.u;
      }
      *(u32x4*)&NX[wave * 8 + pr][lane * 4] = w4;
    }
  }

  f32x4 acc[4][3];
#pragma unroll
  for (int i = 0; i < 4; ++i)
#pragma unroll
    for (int j = 0; j < 3; ++j)
      acc[i][j] = (f32x4){0.f, 0.f, 0.f, 0.f};

  __syncthreads();  // barrier #1: staging complete

  const int ghalf = q8 >> 1;      // g = 2*ks + ghalf
  const int ipof = (q8 & 1) * 4;  // ipair offset for this lane's 8 i's
  const int wp = wave * 48 + col;
  const half2_t one2 = {(__fp16)1.f, (__fp16)1.f};
  const half2_t zero2 = {(__fp16)0.f, (__fp16)0.f};

  // ---- main loop: pure LDS + VALU + MFMA; no global memory, no barriers ----
#pragma unroll
  for (int c = 0; c < NCHUNK; ++c) {
    uint32_t nxp[3][4];
#pragma unroll
    for (int pti = 0; pti < 3; ++pti)
#pragma unroll
      for (int jj = 0; jj < 4; ++jj)
        nxp[pti][jj] = NX[c * 8 + ipof + jj][wp + pti * 16];  // conflict-free

#pragma unroll
    for (int ks = 0; ks < 3; ++ks) {
      half8_t af[4];
#pragma unroll
      for (int ot = 0; ot < 4; ++ot)
        af[ot] = *(const half8_t*)&A_lds[ot * 16 + col][c * KC + ks * 32 + q8 * 8];

      const __fp16 gh = (__fp16)(float)(2 * ks + ghalf);
      const half2_t gf2 = {gh, gh};
#pragma unroll
      for (int pti = 0; pti < 3; ++pti) {
        union { half2_t h2[4]; half8_t v; } bu;
#pragma unroll
        for (int jj = 0; jj < 4; ++jj) {
          union { uint32_t u; half2_t h; } nx;
          nx.u = nxp[pti][jj];
          half2_t d = nx.h - gf2;                 // v_pk_add_f16
          union { half2_t h; uint32_t u; } du;
          du.h = d;
          du.u &= 0x7FFF7FFFu;                    // packed |.|
          half2_t hh = one2 - du.h;               // v_pk_add_f16
          bu.h2[jj] = __builtin_elementwise_max(hh, zero2);  // v_pk_max_f16
        }
#pragma unroll
        for (int ot = 0; ot < 4; ++ot)
          acc[ot][pti] = __builtin_amdgcn_mfma_f32_16x16x32_f16(
              af[ot], bu.v, acc[ot][pti], 0, 0, 0);
      }
    }
  }

  // ==== epilogue (verbatim v11): transpose through LDS, coalesced nt stores ====
  __syncthreads();  // barrier #2: all waves done reading A_lds -> safe to overlay
  float* S = (float*)&A_lds[0][0];  // S[64][SROW=196] f32 = 50176 B, exact fit
#pragma unroll
  for (int ot = 0; ot < 4; ++ot) {
#pragma unroll
    for (int pti = 0; pti < 3; ++pti) {
      int p = wave * 48 + pti * 16 + col;
#pragma unroll
      for (int r = 0; r < 4; ++r) {
        int o = ot * 16 + q8 * 4 + r;
        S[o * SROW + p] = acc[ot][pti][r];  // 2-way banks (q8-step 784%32=16)
      }
    }
  }
  __syncthreads();  // barrier #3

  // wave w stores o-rows [16w,16w+16): 12 x 1KB flat-contiguous instructions,
  // each 2-3 full-line (>=256B) global segments. nt: don't pollute L3.
  {
    float* ob = out + (size_t)b * OD * PIX + p0;
#pragma unroll
    for (int k = 0; k < 12; ++k) {
      int flat = wave * 12288 + k * 1024 + lane * 16;  // byte offset in 64x768 tile
      int row = flat / 768;                            // magic-mul, no div
      int colw = (flat - row * 768) >> 2;              // word col 0..191
      f32x4 v = *(const f32x4*)&S[row * SROW + colw];
      __builtin_nontemporal_store(v, (f32x4*)(ob + (size_t)row * PIX + colw));
    }
  }
}

extern "C" void kernel_launch(void* const* d_in, const int* in_sizes, int n_in,
                              void* d_out, int out_size, void* d_ws, size_t ws_size,
                              hipStream_t stream) {
  const float* x = (const float*)d_in[0];
  const float* coef = (const float*)d_in[1];
  float* out = (float*)d_out;
  dim3 grid(NBATCH * PTILES);
  dim3 block(256);
  hipLaunchKernelGGL(kan_mfma, grid, block, 0, stream, x, coef, out);
}